// Round 3
// baseline (12386.923 us; speedup 1.0000x reference)
//
#include <hip/hip_runtime.h>
#include <stdint.h>

#define Tt 1024
#define Bt 128
#define Vt 256

typedef __attribute__((ext_vector_type(8))) short bf16x8;
typedef __attribute__((ext_vector_type(4))) float f32x4;
typedef __attribute__((ext_vector_type(4))) unsigned int u32x4;

__device__ __forceinline__ unsigned short f2bf(float f) {
    unsigned u = __builtin_bit_cast(unsigned, f);
    u += 0x7fffu + ((u >> 16) & 1u);
    return (unsigned short)(u >> 16);
}
__device__ __forceinline__ float sigm(float x) { return 1.f / (1.f + __expf(-x)); }
__device__ __forceinline__ float tanh_f(float x) {
    float e = __expf(-2.f * fabsf(x));
    float t = (1.f - e) / (1.f + e);
    return copysignf(t, x);
}

// Buffer resource over a flat buffer, bounds check disabled (num_records=-1),
// word3 = 0x00020000 (raw untyped dword access).
__device__ __forceinline__ __amdgpu_buffer_rsrc_t make_srd(const void* p) {
    return __builtin_amdgcn_make_buffer_rsrc(const_cast<void*>(p), (short)0,
                                             0xffffffffu, 0x00020000u);
}
// aux=17 -> sc0|sc1: bypass L1+L2, serve at MALL (agent-coherent). Same CPol
// the R1 __hip_atomic_* path used (HW-validated), but fully pipelined.
__device__ __forceinline__ bf16x8 ld_frag(__amdgpu_buffer_rsrc_t srd, int voff) {
    u32x4 v = __builtin_amdgcn_raw_buffer_load_b128(srd, voff, 0, 17);
    return __builtin_bit_cast(bf16x8, v);
}
// Spin until all 32 producer bytes of one wave-slice block are 1.
__device__ __forceinline__ void wait_block32(__amdgpu_buffer_rsrc_t srdF, int off) {
    for (;;) {
        u32x4 a = __builtin_amdgcn_raw_buffer_load_b128(srdF, off, 0, 17);
        u32x4 b = __builtin_amdgcn_raw_buffer_load_b128(srdF, off + 16, 0, 17);
        unsigned x = a.x & a.y & a.z & a.w & b.x & b.y & b.z & b.w;
        if (x == 0x01010101u) return;
        __builtin_amdgcn_s_sleep(1);
        asm volatile("" ::: "memory");
    }
}

// ---------------- x [B,T,V] fp32 -> xT [T,B,V] bf16 ----------------
__global__ __launch_bounds__(256) void cvt_kernel(const float* __restrict__ x,
                                                  unsigned short* __restrict__ xT) {
    unsigned g = blockIdx.x * 256u + threadIdx.x;
    unsigned base = g * 8u;
    unsigned r = base >> 8;      // r = t*128 + b
    unsigned v = base & 255u;
    unsigned t = r >> 7, b = r & 127u;
    const float4* src = (const float4*)(x + ((size_t)b * Tt + t) * Vt + v);
    float4 f0 = src[0], f1 = src[1];
    union { unsigned short s[8]; int4 q; } o;
    o.s[0] = f2bf(f0.x); o.s[1] = f2bf(f0.y); o.s[2] = f2bf(f0.z); o.s[3] = f2bf(f0.w);
    o.s[4] = f2bf(f1.x); o.s[5] = f2bf(f1.y); o.s[6] = f2bf(f1.z); o.s[7] = f2bf(f1.w);
    *(int4*)(xT + (size_t)r * Vt + v) = o.q;
}

// ---------------- persistent dataflow recurrence: 64 WGs ----------------
// wg 0..31 layer1, wg 32..63 layer2; WG sub owns h-cols [8*sub, 8*sub+8).
// Wave w handles batch rows [32w,32w+32) -> 4 independent wave-slices, no
// intra-WG barriers in the tick loop. Flags: 1 byte per (t, wave, sub).
__global__ __launch_bounds__(256) void rec_kernel(
    const float* __restrict__ Wih1, const float* __restrict__ Whh1,
    const float* __restrict__ bih1, const float* __restrict__ bhh1,
    const float* __restrict__ Wih2, const float* __restrict__ Whh2,
    const float* __restrict__ bih2, const float* __restrict__ bhh2,
    const unsigned short* __restrict__ xT,
    unsigned short* h1s, unsigned short* h2s,
    unsigned char* flags1, unsigned char* flags2) {
    const int wg = blockIdx.x;
    const int layer = wg >> 5;
    const int sub = wg & 31;
    const int hc0 = sub * 8;
    const float* Win = layer ? Wih2 : Wih1;
    const float* Whh = layer ? Whh2 : Whh1;
    const float* bi = layer ? bih2 : bih1;
    const float* bh = layer ? bhh2 : bhh1;

    // frag-major LDS layout: idx(nb,kb,q,ln,e) = (((nb*8+kb)*4+q)*16+ln)*8+e
    // -> every wave ds_read_b128 is lane-contiguous (conflict-free pattern).
    __shared__ unsigned short sWin[8192];
    __shared__ unsigned short sWhh[8192];

    const int tid = threadIdx.x;
    {
        int m = tid >> 7;            // 0: Win, 1: Whh
        int lr = (tid >> 2) & 31;    // N index 0..31
        int seg = tid & 3;           // K segment seg*64..
        int nb = lr >> 4, lnn = lr & 15;
        int grp = lr >> 3, local = lr & 7;
        int grow = 256 * grp + hc0 + local;
        const float* src = (m ? Whh : Win) + (size_t)grow * Vt + seg * 64;
        unsigned short* dstbase = m ? sWhh : sWin;
        for (int k0 = 0; k0 < 64; k0 += 4) {
            int k = seg * 64 + k0;
            float4 f = *(const float4*)(src + k0);
            int kb = k >> 5, qq = (k >> 3) & 3, e = k & 7;
            unsigned short* dst = dstbase + ((((nb * 8 + kb) * 4 + qq) * 16 + lnn) * 8 + e);
            dst[0] = f2bf(f.x); dst[1] = f2bf(f.y);
            dst[2] = f2bf(f.z); dst[3] = f2bf(f.w);
        }
    }
    __syncthreads();   // weights read-only afterwards

    const int lane = tid & 63;
    const int w = tid >> 6;          // wave 0..3 -> batch rows [32w, 32w+32)
    const int q = lane >> 4;
    const int ln = lane & 15;
    const int myrb = ln >> 3;        // row-block handled by this lane in epilogue
    const int lcol = hc0 + (ln & 7);

    float biasv[2];
    for (int nb = 0; nb < 2; ++nb) {
        int grp = nb * 2 + (ln >> 3);
        int grow = 256 * grp + hc0 + (ln & 7);
        biasv[nb] = bi[grow] + bh[grow];
    }

    float cst[4] = {0.f, 0.f, 0.f, 0.f};

    const int rowoff0 = (32 * w + ln) * 256 + q * 8;   // shorts
    const int rowoff1 = rowoff0 + 16 * 256;

    __amdgpu_buffer_rsrc_t srdH1 = make_srd(h1s);
    __amdgpu_buffer_rsrc_t srdH2 = make_srd(h2s);
    __amdgpu_buffer_rsrc_t srdF1 = make_srd(flags1);
    __amdgpu_buffer_rsrc_t srdF2 = make_srd(flags2);
    __amdgpu_buffer_rsrc_t srdOut = layer ? srdH2 : srdH1;
    __amdgpu_buffer_rsrc_t srdFmine = layer ? srdF2 : srdF1;

    for (int t = 0; t < Tt; ++t) {
        f32x4 acc[2][2];
        for (int rb = 0; rb < 2; ++rb)
            for (int nb = 0; nb < 2; ++nb)
                acc[rb][nb] = (f32x4){biasv[nb], biasv[nb], biasv[nb], biasv[nb]};

        bf16x8 ain[2][8];
        bf16x8 ah[2][8];
        const bool have_h = (t > 0);
        const int tB = t * (Bt * Vt);

        if (layer == 0) {
            const unsigned short* xp = xT + (size_t)tB;
            for (int kb = 0; kb < 8; ++kb) {
                ain[0][kb] = *(const bf16x8*)(xp + rowoff0 + kb * 32);
                ain[1][kb] = *(const bf16x8*)(xp + rowoff1 + kb * 32);
            }
            if (have_h) {
                if (lane == 0) wait_block32(srdF1, (t - 1) * 128 + w * 32);
                asm volatile("" ::: "memory");
                int pb = (tB - Bt * Vt) * 2;
                for (int kb = 0; kb < 8; ++kb) {
                    ah[0][kb] = ld_frag(srdH1, pb + (rowoff0 + kb * 32) * 2);
                    ah[1][kb] = ld_frag(srdH1, pb + (rowoff1 + kb * 32) * 2);
                }
            }
        } else {
            if (lane == 0) {
                wait_block32(srdF1, t * 128 + w * 32);
                if (have_h) wait_block32(srdF2, (t - 1) * 128 + w * 32);
            }
            asm volatile("" ::: "memory");
            int cb = tB * 2;
            for (int kb = 0; kb < 8; ++kb) {
                ain[0][kb] = ld_frag(srdH1, cb + (rowoff0 + kb * 32) * 2);
                ain[1][kb] = ld_frag(srdH1, cb + (rowoff1 + kb * 32) * 2);
            }
            if (have_h) {
                int pb = (tB - Bt * Vt) * 2;
                for (int kb = 0; kb < 8; ++kb) {
                    ah[0][kb] = ld_frag(srdH2, pb + (rowoff0 + kb * 32) * 2);
                    ah[1][kb] = ld_frag(srdH2, pb + (rowoff1 + kb * 32) * 2);
                }
            }
        }

        // input-projection GEMM (B-frags: lane-contiguous LDS reads)
        for (int kb = 0; kb < 8; ++kb) {
            bf16x8 b0 = *(const bf16x8*)(sWin + ((kb * 4 + q) * 16 + ln) * 8);
            bf16x8 b1 = *(const bf16x8*)(sWin + 4096 + ((kb * 4 + q) * 16 + ln) * 8);
            acc[0][0] = __builtin_amdgcn_mfma_f32_16x16x32_bf16(ain[0][kb], b0, acc[0][0], 0, 0, 0);
            acc[1][0] = __builtin_amdgcn_mfma_f32_16x16x32_bf16(ain[1][kb], b0, acc[1][0], 0, 0, 0);
            acc[0][1] = __builtin_amdgcn_mfma_f32_16x16x32_bf16(ain[0][kb], b1, acc[0][1], 0, 0, 0);
            acc[1][1] = __builtin_amdgcn_mfma_f32_16x16x32_bf16(ain[1][kb], b1, acc[1][1], 0, 0, 0);
        }
        // recurrent GEMM
        if (have_h) {
            for (int kb = 0; kb < 8; ++kb) {
                bf16x8 b0 = *(const bf16x8*)(sWhh + ((kb * 4 + q) * 16 + ln) * 8);
                bf16x8 b1 = *(const bf16x8*)(sWhh + 4096 + ((kb * 4 + q) * 16 + ln) * 8);
                acc[0][0] = __builtin_amdgcn_mfma_f32_16x16x32_bf16(ah[0][kb], b0, acc[0][0], 0, 0, 0);
                acc[1][0] = __builtin_amdgcn_mfma_f32_16x16x32_bf16(ah[1][kb], b0, acc[1][0], 0, 0, 0);
                acc[0][1] = __builtin_amdgcn_mfma_f32_16x16x32_bf16(ah[0][kb], b1, acc[0][1], 0, 0, 0);
                acc[1][1] = __builtin_amdgcn_mfma_f32_16x16x32_bf16(ah[1][kb], b1, acc[1][1], 0, 0, 0);
            }
        }

        // LSTM cell: lane pair (ln, ln+8) splits the two row-blocks.
        for (int r = 0; r < 4; ++r) {
            float own0 = acc[myrb][0][r], own1 = acc[myrb][1][r];
            float snd0 = acc[1 - myrb][0][r], snd1 = acc[1 - myrb][1][r];
            float rcv0 = __shfl_xor(snd0, 8);
            float rcv1 = __shfl_xor(snd1, 8);
            float iv = myrb ? rcv0 : own0;
            float fv = myrb ? own0 : rcv0;
            float gv = myrb ? rcv1 : own1;
            float ov = myrb ? own1 : rcv1;
            float cc = sigm(fv) * cst[r] + sigm(iv) * tanh_f(gv);
            cst[r] = cc;
            float hh = sigm(ov) * tanh_f(cc);
            int row = 32 * w + myrb * 16 + q * 4 + r;
            int voff = (tB + row * 256 + lcol) * 2;
            __builtin_amdgcn_raw_buffer_store_b16(f2bf(hh), srdOut, voff, 0, 17);
        }

        // drain h stores to MALL, then publish this wave's flag byte
        asm volatile("s_waitcnt vmcnt(0)" ::: "memory");
        if (lane == 0)
            __builtin_amdgcn_raw_buffer_store_b8((unsigned char)1, srdFmine,
                                                 t * 128 + w * 32 + sub, 0, 17);
    }
}

// ---------------- out[b,t,:] = h2s[t,b,:] @ w_n^T + fc_b ----------------
__global__ __launch_bounds__(256) void fc_kernel(const unsigned short* __restrict__ h2s,
                                                 const float* __restrict__ fcw,
                                                 const float* __restrict__ fcb,
                                                 float* __restrict__ out) {
    const int bid = blockIdx.x;
    const int rb = bid >> 2;             // t
    const int c0 = (bid & 3) * 64;
    __shared__ unsigned short sW[64][264];
    __shared__ float sInv[64];
    const int tid = threadIdx.x;
    if (tid < 64) {
        const float* wr = fcw + (size_t)(c0 + tid) * 256;
        float s = 0.f;
        for (int k = 0; k < 256; k += 4) {
            float4 f = *(const float4*)(wr + k);
            s += f.x * f.x + f.y * f.y + f.z * f.z + f.w * f.w;
        }
        sInv[tid] = rsqrtf(s);
    }
    __syncthreads();
    {
        int lr = tid & 63, seg = tid >> 6;
        float inv = sInv[lr];
        const float* wr = fcw + (size_t)(c0 + lr) * 256 + seg * 64;
        unsigned short* dst = &sW[lr][seg * 64];
        for (int k = 0; k < 64; k += 4) {
            float4 f = *(const float4*)(wr + k);
            dst[k + 0] = f2bf(f.x * inv); dst[k + 1] = f2bf(f.y * inv);
            dst[k + 2] = f2bf(f.z * inv); dst[k + 3] = f2bf(f.w * inv);
        }
    }
    __syncthreads();
    const int lane = tid & 63, w = tid >> 6, q = lane >> 4, ln = lane & 15;
    f32x4 acc[2][4];
    for (int rk = 0; rk < 2; ++rk)
        for (int nb = 0; nb < 4; ++nb) {
            float bv = fcb[c0 + nb * 16 + ln];
            acc[rk][nb] = (f32x4){bv, bv, bv, bv};
        }
    const unsigned short* ap = h2s + (size_t)rb * (Bt * Vt);
    for (int kb = 0; kb < 8; ++kb) {
        bf16x8 a0 = *(const bf16x8*)(ap + (32 * w + ln) * 256 + kb * 32 + q * 8);
        bf16x8 a1 = *(const bf16x8*)(ap + (32 * w + 16 + ln) * 256 + kb * 32 + q * 8);
        for (int nb = 0; nb < 4; ++nb) {
            bf16x8 b = *(const bf16x8*)&sW[nb * 16 + ln][kb * 32 + q * 8];
            acc[0][nb] = __builtin_amdgcn_mfma_f32_16x16x32_bf16(a0, b, acc[0][nb], 0, 0, 0);
            acc[1][nb] = __builtin_amdgcn_mfma_f32_16x16x32_bf16(a1, b, acc[1][nb], 0, 0, 0);
        }
    }
    for (int rk = 0; rk < 2; ++rk)
        for (int nb = 0; nb < 4; ++nb)
            for (int r = 0; r < 4; ++r) {
                int bb = 32 * w + rk * 16 + q * 4 + r;
                int o = c0 + nb * 16 + ln;
                out[((size_t)bb * Tt + rb) * 256 + o] = acc[rk][nb][r];
            }
}

extern "C" void kernel_launch(void* const* d_in, const int* in_sizes, int n_in,
                              void* d_out, int out_size, void* d_ws, size_t ws_size,
                              hipStream_t stream) {
    const float* x    = (const float*)d_in[0];
    const float* Wih1 = (const float*)d_in[1];
    const float* Whh1 = (const float*)d_in[2];
    const float* bih1 = (const float*)d_in[3];
    const float* bhh1 = (const float*)d_in[4];
    const float* Wih2 = (const float*)d_in[5];
    const float* Whh2 = (const float*)d_in[6];
    const float* bih2 = (const float*)d_in[7];
    const float* bhh2 = (const float*)d_in[8];
    const float* fcw  = (const float*)d_in[9];
    const float* fcb  = (const float*)d_in[10];

    char* ws = (char*)d_ws;
    unsigned char* flags1 = (unsigned char*)ws;                 // 1024*128 B
    unsigned char* flags2 = (unsigned char*)(ws + 131072);      // 1024*128 B
    unsigned short* xT  = (unsigned short*)(ws + 262144);
    unsigned short* h1s = xT + (size_t)Tt * Bt * Vt;
    unsigned short* h2s = h1s + (size_t)Tt * Bt * Vt;

    (void)hipMemsetAsync(ws, 0, 262144, stream);
    cvt_kernel<<<16384, 256, 0, stream>>>(x, xT);
    rec_kernel<<<64, 256, 0, stream>>>(Wih1, Whh1, bih1, bhh1,
                                       Wih2, Whh2, bih2, bhh2,
                                       xT, h1s, h2s, flags1, flags2);
    fc_kernel<<<4096, 256, 0, stream>>>(h2s, fcw, fcb, (float*)d_out);
}